// Round 1
// 361.130 us; speedup vs baseline: 1.1180x; 1.1180x over previous
//
#include <hip/hip_runtime.h>
#include <hip/hip_bf16.h>

typedef __attribute__((ext_vector_type(8))) short short8;
typedef __attribute__((ext_vector_type(4))) float float4v;

#define NSAMP 10000
#define CIN   64
#define TLEN  64
#define COUT  64     // channels after GLU
#define TOUT  62

// fp32 -> bf16 bits, round-to-nearest-even (inputs are never NaN/Inf)
static __device__ __forceinline__ ushort f2bf(float v) {
    unsigned int x = __float_as_uint(v);
    return (ushort)((x + 0x7fffu + ((x >> 16) & 1u)) >> 16);
}

// packed fp32x2 -> bf16x2 (lo = a, hi = b), RNE
static __device__ __forceinline__ unsigned int cvt_pk_bf16(float a, float b) {
    unsigned int r;
    asm("v_cvt_pk_bf16_f32 %0, %1, %2" : "=v"(r) : "v"(a), "v"(b));
    return r;
}

// Pre-permute + downconvert weights: Wa[co][kk], kk = k*64 + ci (bf16 bits).
// src: float w[co][ci][k] (strides 192, 3, 1)
__global__ void prep_weights(const float* __restrict__ w, ushort* __restrict__ wa) {
    int o = blockIdx.x * blockDim.x + threadIdx.x;
    if (o >= 128 * 192) return;
    int co = o / 192;
    int kk = o - co * 192;
    int k  = kk >> 6;
    int ci = kk & 63;
    wa[o] = f2bf(w[co * 192 + ci * 3 + k]);
}

// One sample per block. 4 waves: (w&1) = co-half, (w>>1) = t-half.
// Wave (h, nh): co in [32h,32h+32) U [32h+64,32h+96) (GLU pairs in-wave),
// t in [32*nh, 32*nh+32).
//
// x is staged ONCE per block into LDS as bf16, transposed to [t][ci]
// (rows of 64 ci * 2B = 128B), with XOR row-swizzle byte ^= ((t&7)<<4)
// so the stride-128B ds_read_b128 column reads are bank-uniform.
// B fragments then are single ds_read_b128 ops (was: 8 scalar global
// gathers + 8 scalar f2bf per fragment).
__global__ __launch_bounds__(256, 4)
void conv_glu(const float* __restrict__ x, const ushort* __restrict__ wa,
              const float* __restrict__ bias, float* __restrict__ out) {
    __shared__ __align__(16) ushort xT[64 * 64];   // 8 KB

    const int n   = blockIdx.x;
    const int tid = threadIdx.x;
    const int w   = tid >> 6;      // wave id 0..3
    const int L   = tid & 63;      // lane
    const int l   = L & 15;
    const int q   = L >> 4;        // quad
    const int h   = w & 1;         // M half
    const int nh  = w >> 1;        // N half
    const int t0base = nh * 32;

    const float* xs = x + n * (CIN * TLEN);

    // ---- Stage x -> LDS: bf16, transposed [t][ci], XOR-swizzled rows ----
    // Each thread: 4x4 (ci x t) tile. 4 coalesced float4 loads,
    // 8 packed cvt, 4 ds_write_b64.
    {
        const int cig = tid >> 4;         // ci group of 4: ci = cig*4 + j
        const int ts  = (tid & 15) * 4;   // t base
        const float* p = xs + cig * 4 * TLEN + ts;
        float4v v0 = *(const float4v*)(p);
        float4v v1 = *(const float4v*)(p + TLEN);
        float4v v2 = *(const float4v*)(p + 2 * TLEN);
        float4v v3 = *(const float4v*)(p + 3 * TLEN);
        char* base = (char*)xT;
#pragma unroll
        for (int r = 0; r < 4; ++r) {
            int t = ts + r;
            uint2 val;
            val.x = cvt_pk_bf16(v0[r], v1[r]);   // ci 4cig, 4cig+1
            val.y = cvt_pk_bf16(v2[r], v3[r]);   // ci 4cig+2, 4cig+3
            *(uint2*)(base + t * 128 + ((cig * 8) ^ ((t & 7) << 4))) = val;
        }
    }
    __syncthreads();

    // A-fragment row pointers (bf16 weights, L1/L2-hot). Per-kc loads use
    // immediate offsets off these bases.
    const ushort* arow[4];
#pragma unroll
    for (int mt = 0; mt < 4; ++mt) {
        int co = 32 * h + 16 * (mt & 1) + 64 * (mt >> 1) + l;
        arow[mt] = wa + co * 192 + q * 8;
    }

    float4v acc[4][2];
#pragma unroll
    for (int mt = 0; mt < 4; ++mt)
#pragma unroll
        for (int nt = 0; nt < 2; ++nt)
            acc[mt][nt] = (float4v){0.f, 0.f, 0.f, 0.f};

    // K loop: chunk kc covers conv-tap k = kc>>1, ci base = (kc&1)*32.
    // A layout: A[m=lane&15][k=q*8+j]; B layout: B[k=q*8+j][n=lane&15].
#pragma unroll
    for (int kc = 0; kc < 6; ++kc) {
        short8 afr[4];
#pragma unroll
        for (int mt = 0; mt < 4; ++mt)
            afr[mt] = *(const short8*)(arow[mt] + kc * 32);

        const int tap  = kc >> 1;
        const int cib2 = (kc & 1) * 64 + q * 16;   // byte offset of ci-slice
#pragma unroll
        for (int nt = 0; nt < 2; ++nt) {
            int t = t0base + nt * 16 + l + tap;
            if (t > 63) t = 63;                    // pad cols (t>=62 discarded)
            const short8 bfr = *(const short8*)((const char*)xT + t * 128
                                                + (cib2 ^ ((t & 7) << 4)));
#pragma unroll
            for (int mt = 0; mt < 4; ++mt)
                acc[mt][nt] = __builtin_amdgcn_mfma_f32_16x16x32_bf16(
                    afr[mt], bfr, acc[mt][nt], 0, 0, 0);
        }
    }

    // Epilogue: bias + GLU. Pair (mt, mt+2) = (value co, gate co+64). fp32 store.
    // D layout: row = q*4 + r, col = l.
#pragma unroll
    for (int p2 = 0; p2 < 2; ++p2) {
#pragma unroll
        for (int nt = 0; nt < 2; ++nt) {
#pragma unroll
            for (int r = 0; r < 4; ++r) {
                int co = 32 * h + 16 * p2 + 4 * q + r;
                int t  = t0base + nt * 16 + l;
                float a = acc[p2][nt][r]     + bias[co];
                float g = acc[p2 + 2][nt][r] + bias[co + 64];
                float sg = 1.0f / (1.0f + __expf(-g));
                if (t < TOUT)
                    out[(n * COUT + co) * TOUT + t] = a * sg;
            }
        }
    }
}

extern "C" void kernel_launch(void* const* d_in, const int* in_sizes, int n_in,
                              void* d_out, int out_size, void* d_ws, size_t ws_size,
                              hipStream_t stream) {
    const float* x    = (const float*)d_in[0];
    const float* wt   = (const float*)d_in[1];
    const float* bias = (const float*)d_in[2];
    ushort*      wa   = (ushort*)d_ws;        // 48 KB permuted bf16 weights
    float*       out  = (float*)d_out;

    prep_weights<<<96, 256, 0, stream>>>(wt, wa);
    conv_glu<<<NSAMP, 256, 0, stream>>>(x, wa, bias, out);
}